// Round 3
// baseline (1619.988 us; speedup 1.0000x reference)
//
#include <hip/hip_runtime.h>
#include <hip/hip_bf16.h>

// GAT_52673478918844 — 2-layer GAT, N=100k, E=1.6M.
// ws layout (46.0 MB):
//   +0        flag (int, padded to 256B)
//   +256      hC    : bf16 N x 128 (feat1 -> h), 25.6 MB
//   +25.6M    B     : layer-1 f32 acc (N x 32) / later feat2 bf16 (N x 64), 12.8 MB
//   +38.4M    C     : layer-2 f32 acc (N x 16), 6.4 MB
//   +44.8M    D     : el2, er2, d2 (f32 N each), 1.2 MB
// d_out doubles as scratch for el1/er1/d1 (9.6 MB <= 12.8 MB) until final store.

#define NN 100000
#define NE 1600000

typedef unsigned short u16;
typedef unsigned int   u32;

__device__ __forceinline__ float bf2f(u16 u) { return __uint_as_float(((u32)u) << 16); }
__device__ __forceinline__ u16 f2bf(float f) {
    u32 u = __float_as_uint(f);
    return (u16)((u + 0x7fffu + ((u >> 16) & 1u)) >> 16);   // RNE
}
__device__ __forceinline__ float lrelu(float v) { return v > 0.f ? v : 0.2f * v; }
// dual-dtype load: isf32 ? f32[i] : bf16[i]
__device__ __forceinline__ float loadf(const void* p, size_t i, int isf32) {
    return isf32 ? ((const float*)p)[i] : bf2f(((const u16*)p)[i]);
}

// ---- dtype autodetect: bf16 x ~ N(0,1) -> mean|x| ~ 0.8 ; f32-misread -> ~2e5 ----
__global__ void k_detect(const u16* __restrict__ x, int* __restrict__ flag)
{
    __shared__ float s[256];
    int t = threadIdx.x;
    float a = 0.f;
    for (int i = t; i < 1024; i += 256) a += fminf(fabsf(bf2f(x[i])), 1e6f);
    s[t] = a;
    __syncthreads();
    if (t == 0) {
        float tot = 0.f;
        for (int i = 0; i < 256; ++i) tot += s[i];
        *flag = (tot * (1.f / 1024.f) > 100.f) ? 1 : 0;
    }
}

// ---- beacon: fill output with a recognizable constant ----
__global__ void k_beacon(u16* __restrict__ out, int n, float code)
{
    int tid = blockIdx.x * 256 + threadIdx.x;
    if (tid < n) out[tid] = f2bf(code);
}

// ---- GEMM1: feat1 = x @ W1 -> hC (bf16) + el1/er1 (f32) ----
__global__ __launch_bounds__(256) void k_gemm1(
    const void* __restrict__ x, const void* __restrict__ W1,
    const void* __restrict__ al1, const void* __restrict__ ar1,
    const int* __restrict__ flag,
    u16* __restrict__ hC, float* __restrict__ el1, float* __restrict__ er1)
{
    __shared__ u16 wS[128 * 128];                  // 32 KB (bf16 bits)
    __shared__ __align__(16) float xS[128 * 36];   // 18 KB; reused as featbuf[32][128]
    __shared__ float alS[128], arS[128];
    const int t  = threadIdx.x;
    const int r0 = blockIdx.x * 32;                // 3125 * 32 = 100000
    const int isf32 = *flag;

    for (int i = t; i < 128 * 128; i += 256)
        wS[i] = isf32 ? f2bf(((const float*)W1)[i]) : ((const u16*)W1)[i];
    if (t < 128) { alS[t] = loadf(al1, t, isf32); arS[t] = loadf(ar1, t, isf32); }
    for (int i = t; i < 32 * 128; i += 256) {
        int r = i >> 7, k = i & 127;
        xS[k * 36 + r] = loadf(x, (size_t)(r0 + r) * 128 + k, isf32);
    }
    __syncthreads();

    const int c = t & 127, rh = t >> 7;
    float acc[16];
    #pragma unroll
    for (int i = 0; i < 16; ++i) acc[i] = 0.f;

    for (int k = 0; k < 128; ++k) {
        float wv = bf2f(wS[k * 128 + c]);
        const float4* xp = (const float4*)&xS[k * 36 + rh * 16];
        float4 a0 = xp[0], a1 = xp[1], a2 = xp[2], a3 = xp[3];
        acc[0]  += a0.x * wv; acc[1]  += a0.y * wv; acc[2]  += a0.z * wv; acc[3]  += a0.w * wv;
        acc[4]  += a1.x * wv; acc[5]  += a1.y * wv; acc[6]  += a1.z * wv; acc[7]  += a1.w * wv;
        acc[8]  += a2.x * wv; acc[9]  += a2.y * wv; acc[10] += a2.z * wv; acc[11] += a2.w * wv;
        acc[12] += a3.x * wv; acc[13] += a3.y * wv; acc[14] += a3.z * wv; acc[15] += a3.w * wv;
    }
    __syncthreads();

    #pragma unroll
    for (int i = 0; i < 16; ++i) {
        int r = rh * 16 + i;
        hC[(size_t)(r0 + r) * 128 + c] = f2bf(acc[i]);
        xS[r * 128 + c] = acc[i];                  // f32 featbuf for el/er
    }
    __syncthreads();

    const int r = t >> 3, hh = t & 7;
    float el = 0.f, er = 0.f;
    #pragma unroll
    for (int dd = 0; dd < 16; ++dd) {
        float f = xS[r * 128 + hh * 16 + dd];
        el += f * alS[hh * 16 + dd];
        er += f * arS[hh * 16 + dd];
    }
    el1[(r0 + r) * 8 + hh] = el;
    er1[(r0 + r) * 8 + hh] = er;
}

// ---- layer-1 softmax denominators ----
__global__ __launch_bounds__(256) void k_denom1(
    const int* __restrict__ src, const int* __restrict__ dst,
    const float* __restrict__ el1, const float* __restrict__ er1,
    float* __restrict__ d1)
{
    int tid = blockIdx.x * 256 + threadIdx.x;      // < NE*8
    int e = tid >> 3, hh = tid & 7;
    int s = src[e], d = dst[e];
    atomicAdd(&d1[d * 8 + hh], __expf(lrelu(el1[s * 8 + hh] + er1[d * 8 + hh])));
}

// ---- layer-1 aggregation, one 32-col quarter ----
__global__ __launch_bounds__(256) void k_agg1(
    const int* __restrict__ src, const int* __restrict__ dst,
    const float* __restrict__ el1, const float* __restrict__ er1,
    const float* __restrict__ d1, const u16* __restrict__ feat1,
    float* __restrict__ acc, int cb)
{
    int tid = blockIdx.x * 256 + threadIdx.x;      // < NE*32
    int e = tid >> 5, j = tid & 31;
    int gj = cb + j, hh = gj >> 4;
    int s = src[e], d = dst[e];
    float w = __expf(lrelu(el1[s * 8 + hh] + er1[d * 8 + hh]));
    float alpha = w / fmaxf(d1[d * 8 + hh], 1e-9f);
    atomicAdd(&acc[(size_t)d * 32 + j], bf2f(feat1[(size_t)s * 128 + gj]) * alpha);
}

// ---- layer-1 finalize quarter: +bias, ELU -> hC ----
__global__ __launch_bounds__(256) void k_fin1(
    const float* __restrict__ acc, const void* __restrict__ b1,
    const int* __restrict__ flag, u16* __restrict__ hC, int cb)
{
    int tid = blockIdx.x * 256 + threadIdx.x;      // < NN*32
    int r = tid >> 5, j = tid & 31;
    float v = acc[tid] + loadf(b1, cb + j, *flag);
    v = v > 0.f ? v : expm1f(v);
    hC[(size_t)r * 128 + cb + j] = f2bf(v);
}

// ---- GEMM2: feat2 = h @ W2 -> B (bf16) + el2/er2 (f32) ----
__global__ __launch_bounds__(256) void k_gemm2(
    const u16* __restrict__ h, const void* __restrict__ W2,
    const void* __restrict__ al2, const void* __restrict__ ar2,
    const int* __restrict__ flag,
    u16* __restrict__ feat2, float* __restrict__ el2, float* __restrict__ er2)
{
    __shared__ u16 wS[128 * 64];                   // 16 KB
    __shared__ __align__(16) float xS[128 * 36];   // 18 KB
    __shared__ float alS[64], arS[64];
    const int t  = threadIdx.x;
    const int r0 = blockIdx.x * 32;
    const int isf32 = *flag;

    for (int i = t; i < 128 * 64; i += 256)
        wS[i] = isf32 ? f2bf(((const float*)W2)[i]) : ((const u16*)W2)[i];
    if (t < 64) { alS[t] = loadf(al2, t, isf32); arS[t] = loadf(ar2, t, isf32); }
    for (int i = t; i < 32 * 128; i += 256) {
        int r = i >> 7, k = i & 127;
        xS[k * 36 + r] = bf2f(h[(size_t)(r0 + r) * 128 + k]);   // h is OUR bf16 array
    }
    __syncthreads();

    const int c = t & 63, rq = t >> 6;
    float acc[8];
    #pragma unroll
    for (int i = 0; i < 8; ++i) acc[i] = 0.f;

    for (int k = 0; k < 128; ++k) {
        float wv = bf2f(wS[k * 64 + c]);
        const float4* xp = (const float4*)&xS[k * 36 + rq * 8];
        float4 a0 = xp[0], a1 = xp[1];
        acc[0] += a0.x * wv; acc[1] += a0.y * wv; acc[2] += a0.z * wv; acc[3] += a0.w * wv;
        acc[4] += a1.x * wv; acc[5] += a1.y * wv; acc[6] += a1.z * wv; acc[7] += a1.w * wv;
    }
    __syncthreads();

    #pragma unroll
    for (int i = 0; i < 8; ++i) {
        int r = rq * 8 + i;
        feat2[(size_t)(r0 + r) * 64 + c] = f2bf(acc[i]);
        xS[r * 64 + c] = acc[i];
    }
    __syncthreads();

    if (t < 32) {
        float el = 0.f, er = 0.f;
        for (int cc = 0; cc < 64; ++cc) {
            float f = xS[t * 64 + cc];
            el += f * alS[cc]; er += f * arS[cc];
        }
        el2[r0 + t] = el; er2[r0 + t] = er;
    }
}

// ---- layer-2 denominators ----
__global__ __launch_bounds__(256) void k_denom2(
    const int* __restrict__ src, const int* __restrict__ dst,
    const float* __restrict__ el2, const float* __restrict__ er2,
    float* __restrict__ d2)
{
    int tid = blockIdx.x * 256 + threadIdx.x;      // < NE
    int s = src[tid], d = dst[tid];
    atomicAdd(&d2[d], __expf(lrelu(el2[s] + er2[d])));
}

// ---- layer-2 aggregation, one 16-col group ----
__global__ __launch_bounds__(256) void k_msg2(
    const int* __restrict__ src, const int* __restrict__ dst,
    const float* __restrict__ el2, const float* __restrict__ er2,
    const float* __restrict__ d2, const u16* __restrict__ feat2,
    float* __restrict__ acc, int cb)
{
    int tid = blockIdx.x * 256 + threadIdx.x;      // < NE*16
    int e = tid >> 4, j = tid & 15;
    int s = src[e], d = dst[e];
    float w = __expf(lrelu(el2[s] + er2[d]));
    float alpha = w / fmaxf(d2[d], 1e-9f);
    atomicAdd(&acc[(size_t)d * 16 + j], bf2f(feat2[(size_t)s * 64 + cb + j]) * alpha);
}

// ---- layer-2 finalize group: +bias -> out (dtype per flag) ----
__global__ __launch_bounds__(256) void k_fin2(
    const float* __restrict__ acc, const void* __restrict__ b2,
    const int* __restrict__ flag, void* __restrict__ out, int cb)
{
    int tid = blockIdx.x * 256 + threadIdx.x;      // < NN*16
    int r = tid >> 4, j = tid & 15;
    int isf32 = *flag;
    float v = acc[tid] + loadf(b2, cb + j, isf32);
    size_t idx = (size_t)r * 64 + cb + j;
    if (isf32) ((float*)out)[idx] = v;
    else       ((u16*)out)[idx]   = f2bf(v);
}

// ---------------- launch ----------------
extern "C" void kernel_launch(void* const* d_in, const int* in_sizes, int n_in,
                              void* d_out, int out_size, void* d_ws, size_t ws_size,
                              hipStream_t stream)
{
    // ---- host-side gates: beacon codes identify what is wrong via absmax ----
    static const int exp_sizes[11] = {12800000, 1600000, 1600000, 16384, 128, 128, 128, 8192, 64, 64, 64};
    float code = 0.f;
    if (n_in != 11) code = 9000.f;
    else {
        for (int i = 0; i < 11; ++i)
            if (in_sizes[i] != exp_sizes[i]) { code = 3000.f + 100.f * i; break; }
    }
    if (code == 0.f && out_size != 6400000) code = 7777.f;
    if (code == 0.f && ws_size < 46100000)  code = (float)(ws_size >> 20);   // report MB
    if (code != 0.f) {
        k_beacon<<<(out_size + 255) / 256, 256, 0, stream>>>((u16*)d_out, out_size, code);
        return;
    }

    const void* x   = d_in[0];
    const int* src  = (const int*)d_in[1];
    const int* dst  = (const int*)d_in[2];
    const void* W1  = d_in[3];
    const void* al1 = d_in[4];
    const void* ar1 = d_in[5];
    const void* b1  = d_in[6];
    const void* W2  = d_in[7];
    const void* al2 = d_in[8];
    const void* ar2 = d_in[9];
    const void* b2  = d_in[10];

    char* base = (char*)d_ws;
    int*   flag  = (int*)   base;                    // +0
    u16*   hC    = (u16*)  (base + 256);             // 25.6 MB
    float* Bacc  = (float*)(base + 25600256);        // 12.8 MB (layer-1 acc)
    u16*   feat2 = (u16*)  (base + 25600256);        // overlays Bacc (dead by then)
    float* Cacc  = (float*)(base + 38400256);        //  6.4 MB (layer-2 acc)
    float* el2   = (float*)(base + 44800256);        //  0.4 MB
    float* er2   = (float*)(base + 45200256);        //  0.4 MB
    float* d2    = (float*)(base + 45600256);        //  0.4 MB -> 46.0 MB total

    // el1/er1/d1 scratch lives in d_out (9.6 MB <= 12.8 MB), dead before final store
    float* el1 = (float*)d_out;
    float* er1 = el1 + 800000;
    float* d1  = el1 + 1600000;

    k_detect<<<1, 256, 0, stream>>>((const u16*)x, flag);

    k_gemm1<<<3125, 256, 0, stream>>>(x, W1, al1, ar1, flag, hC, el1, er1);

    hipMemsetAsync(d1, 0, (size_t)NN * 8 * 4, stream);
    k_denom1<<<50000, 256, 0, stream>>>(src, dst, el1, er1, d1);

    for (int q = 0; q < 4; ++q) {
        hipMemsetAsync(Bacc, 0, (size_t)NN * 32 * 4, stream);
        k_agg1<<<200000, 256, 0, stream>>>(src, dst, el1, er1, d1, hC, Bacc, q * 32);
        k_fin1<<<12500,  256, 0, stream>>>(Bacc, b1, flag, hC, q * 32);
    }

    k_gemm2<<<3125, 256, 0, stream>>>(hC, W2, al2, ar2, flag, feat2, el2, er2);

    hipMemsetAsync(d2, 0, (size_t)NN * 4, stream);
    k_denom2<<<6250, 256, 0, stream>>>(src, dst, el2, er2, d2);

    for (int p = 0; p < 4; ++p) {
        hipMemsetAsync(Cacc, 0, (size_t)NN * 16 * 4, stream);
        k_msg2<<<100000, 256, 0, stream>>>(src, dst, el2, er2, d2, feat2, Cacc, p * 16);
        k_fin2<<<6250,   256, 0, stream>>>(Cacc, b2, flag, d_out, p * 16);
    }
}